// Round 5
// baseline (210.956 us; speedup 1.0000x reference)
//
#include <hip/hip_runtime.h>

// Problem constants (from reference): B=16, L=4096, D=512, HORIZON=100
constexpr int Bc = 16;
constexpr int Lc = 4096;
constexpr int Dc = 512;
constexpr int F4_PER_ROW = Dc / 4;            // 128 float4 per row
constexpr int CHUNKS = F4_PER_ROW / 2;        // 64: lane p owns float4 p and p+64 of a row
constexpr int ROWS = Bc * (Lc + 1);           // 65552 (even)
constexpr int ROWPAIRS = ROWS / 2;            // 32776
constexpr int TOTALT = ROWPAIRS * CHUNKS;     // 2,097,664 = 8194 * 256 (exact)

// clang native vector type — accepted by __builtin_nontemporal_{load,store}
typedef float v4f __attribute__((ext_vector_type(4)));

__global__ __launch_bounds__(256) void pe_kernel(
    const float* __restrict__ tokens,
    const int*   __restrict__ lengths,
    const float* __restrict__ cls,
    float*       __restrict__ out)
{
    // One wave = TWO consecutive rows (6 KB incl. reads): halves wave count,
    // doubles loads-in-flight, amortizes index math + lengths load + launch cost.
    // Lane p owns float4 #p and #(p+64) of each row -> every instruction is a
    // dense contiguous 1 KB across the wave. Branches stay wave-uniform
    // (a wave touches exactly rows 2w and 2w+1, each uniform across the wave).
    int t  = blockIdx.x * 256 + threadIdx.x;    // grid exact, no tail
    int p  = t & (CHUNKS - 1);                  // float4 index of first chunk (0..63)
    int rp = t >> 6;                            // row-pair index
    int d0 = p << 2;                            // element index (0..252)

    // coef(d) = 100^{-(d - d%2)/512} + (pi/2)*(d%2); in revolutions:
    // freq_rev(d) = exp2(-(d&~1)*log2(100)/512)/(2*pi); phase_rev = 0.25*(d&1)
    // chunk at d+256 scales freq by exactly 0.1.
    const float K      = 6.6438561897747395f / 512.0f;  // log2(100)/512
    const float INV2PI = 0.15915493667125702f;          // 1/(2*pi)
    float f0  = __builtin_exp2f(-(float)(d0    ) * K) * INV2PI;
    float f2  = __builtin_exp2f(-(float)(d0 + 2) * K) * INV2PI;
    float f0b = f0 * 0.1f;
    float f2b = f2 * 0.1f;

    const v4f* tok4 = reinterpret_cast<const v4f*>(tokens);
    const v4f* cls4 = reinterpret_cast<const v4f*>(cls);
    v4f*       out4 = reinterpret_cast<v4f*>(out);

    #pragma unroll
    for (int h = 0; h < 2; ++h) {
        int row = 2 * rp + h;
        int b   = row / (Lc + 1);
        int l   = row - b * (Lc + 1);
        int len = lengths[b];

        v4f r0, r1;
        if (l < len) {
            const v4f* src = tok4 + ((size_t)(b * Lc + l) << 7);
            v4f ta = __builtin_nontemporal_load(src + p);
            v4f tb = __builtin_nontemporal_load(src + p + 64);

            float lf = (float)l;
            r0.x = ta.x + __builtin_amdgcn_sinf(__builtin_amdgcn_fractf(lf * f0));
            r0.y = ta.y + __builtin_amdgcn_sinf(__builtin_amdgcn_fractf(lf * (f0 + 0.25f)));
            r0.z = ta.z + __builtin_amdgcn_sinf(__builtin_amdgcn_fractf(lf * f2));
            r0.w = ta.w + __builtin_amdgcn_sinf(__builtin_amdgcn_fractf(lf * (f2 + 0.25f)));
            r1.x = tb.x + __builtin_amdgcn_sinf(__builtin_amdgcn_fractf(lf * f0b));
            r1.y = tb.y + __builtin_amdgcn_sinf(__builtin_amdgcn_fractf(lf * (f0b + 0.25f)));
            r1.z = tb.z + __builtin_amdgcn_sinf(__builtin_amdgcn_fractf(lf * f2b));
            r1.w = tb.w + __builtin_amdgcn_sinf(__builtin_amdgcn_fractf(lf * (f2b + 0.25f)));
        } else if (l == len) {
            r0 = cls4[p];
            r1 = cls4[p + 64];
        } else {
            r0 = (v4f){0.f, 0.f, 0.f, 0.f};
            r1 = r0;
        }

        v4f* dst = out4 + ((size_t)row << 7);
        __builtin_nontemporal_store(r0, dst + p);
        __builtin_nontemporal_store(r1, dst + p + 64);
    }
}

extern "C" void kernel_launch(void* const* d_in, const int* in_sizes, int n_in,
                              void* d_out, int out_size, void* d_ws, size_t ws_size,
                              hipStream_t stream) {
    const float* tokens  = (const float*)d_in[0];
    const int*   lengths = (const int*)d_in[1];
    const float* cls     = (const float*)d_in[2];
    float*       out     = (float*)d_out;

    int blocks = TOTALT / 256;   // 8194, exact
    pe_kernel<<<blocks, 256, 0, stream>>>(tokens, lengths, cls, out);
}